// Round 10
// baseline (95.163 us; speedup 1.0000x reference)
//
#include <hip/hip_runtime.h>
#include <math.h>

// DynamicTrackHead — R10: single kernel; MLP fused into the last-arriving
// block per instance (modular-wrap atomic, no counter zeroing needed).
// K1: grid (n_inst, NCHUNK=30), block 64 = one wave. 2 threads per pooled
//     pixel (tid>>5 = qy half), 32 pixels/block, BOTH heads per block
//     (shared feature tile). conv0/conv1 in regs; qy-pool via __shfl_xor(32);
//     m1 staged to 2 KB LDS; conv2 one channel/thread/head; 2x64 partials to
//     d_ws. Then: __threadfence(); atomicAdd(cnt[inst]); the block seeing
//     old % 30 == 29 (exactly one per inst per call, any start value) runs
//     the 2-head MLP (fc1 -> LN -> SELU -> fc2) with its 64 threads.
//     Cross-XCD visibility: device-scope atomic + __threadfence release /
//     acquire (buffer_wbl2/buffer_inv sc1 on gfx950).
// params/instance = 736 floats: w0[8][10]@0, w1[8][8]@80, w2[64][8]@144,
// b0@656, b1@664, b2@672.

#define H_IN 96
#define W_IN 160
#define HW_IN (H_IN * W_IN)
#define PW 40            // W_IN / 4
#define PH 24            // H_IN / 4
#define NPIX (PH * PW)   // 960 pooled-twice pixels
#define NCHUNK 30        // K1 blocks per instance
#define CPIX 32          // pooled pixels per K1 block
#define NPARAM 736
#define OW0 0
#define OW1 80
#define OW2 144
#define OB0 656
#define OB1 664
#define OB2 672

#define SELU_SCALE 1.0507009873554805f
#define SELU_ALPHA 1.6732632423543772f

__global__ __launch_bounds__(64, 4) void track_head_fused(
    const float* __restrict__ mask_feats,
    const float* __restrict__ pmain,
    const float* __restrict__ pside,
    const int*   __restrict__ im_inds,
    const float* __restrict__ inst_loc,
    const float* __restrict__ offset_pred,
    const int*   __restrict__ fpn_levels,
    const int*   __restrict__ stride_ptr,
    const float* __restrict__ mw1, const float* __restrict__ mb1,
    const float* __restrict__ mg,  const float* __restrict__ mbeta,
    const float* __restrict__ mw2, const float* __restrict__ mb2,
    const float* __restrict__ sw1, const float* __restrict__ sb1,
    const float* __restrict__ sg,  const float* __restrict__ sbeta,
    const float* __restrict__ sw2, const float* __restrict__ sb2,
    float*       __restrict__ ws_part,       // [n_inst][2][NCHUNK][64]
    unsigned*    __restrict__ cnt,           // [n_inst], never zeroed
    float*       __restrict__ out,
    int n_inst)
{
    const int inst  = blockIdx.x;
    const int chunk = blockIdx.y;
    const int tid   = threadIdx.x;          // 0..63
    const int pix   = tid & 31;             // pixel within chunk
    const int qy    = tid >> 5;             // which pool-2 row half

    __shared__ __align__(16) float s_m1[2][CPIX][8];   // 2 KB (per head)
    __shared__ __align__(16) float s_x[64];
    __shared__ __align__(16) float s_h[128];

    const float* __restrict__ PA = pmain + (size_t)inst * NPARAM;
    const float* __restrict__ PB = pside + (size_t)inst * NPARAM;

    const int S  = stride_ptr[0];
    const int S2 = S / 2;
    const float lxA = inst_loc[inst * 2 + 0];
    const float lyA = inst_loc[inst * 2 + 1];
    const float lxB = lxA + offset_pred[inst * 2 + 0] * 128.0f;
    const float lyB = lyA + offset_pred[inst * 2 + 1] * 128.0f;
    const float inv_soi = 1.0f / (float)(64 << fpn_levels[inst]);
    const float* __restrict__ feat =
        mask_feats + (size_t)im_inds[inst] * 8 * HW_IN;

    const int p   = chunk * CPIX + pix;     // 0..959
    const int py  = p / PW;
    const int px  = p - py * PW;
    const int ix0 = px * 4;
    const int iyb = py * 4 + qy * 2;        // this thread's two input rows

    float x0A[4], x0B[4];
    #pragma unroll
    for (int j = 0; j < 4; j++) {
        const float xc = (float)((ix0 + j) * S + S2);
        x0A[j] = (lxA - xc) * inv_soi;
        x0B[j] = (lxB - xc) * inv_soi;
    }

    // ---- conv0 (relu folded into max): both heads off one feature tile ----
    float m0aA[8], m0bA[8], m0aB[8], m0bB[8];   // quadrant maxes, >= 0
    #pragma unroll
    for (int o = 0; o < 8; o++) {
        m0aA[o] = 0.0f; m0bA[o] = 0.0f;
        m0aB[o] = 0.0f; m0bB[o] = 0.0f;
    }

    #pragma unroll
    for (int sy = 0; sy < 2; sy++) {
        const int iy = iyb + sy;
        const float yc = (float)(iy * S + S2);
        const float x1A = (lyA - yc) * inv_soi;
        const float x1B = (lyB - yc) * inv_soi;
        const float* rowp = feat + iy * W_IN + ix0;
        const float4 f0 = *(const float4*)(rowp + 0 * HW_IN);
        const float4 f1 = *(const float4*)(rowp + 1 * HW_IN);
        const float4 f2 = *(const float4*)(rowp + 2 * HW_IN);
        const float4 f3 = *(const float4*)(rowp + 3 * HW_IN);
        const float4 f4 = *(const float4*)(rowp + 4 * HW_IN);
        const float4 f5 = *(const float4*)(rowp + 5 * HW_IN);
        const float4 f6 = *(const float4*)(rowp + 6 * HW_IN);
        const float4 f7 = *(const float4*)(rowp + 7 * HW_IN);

#define L0_HEAD(P_, X0V, X1, M0A, M0B)                                          \
        {                                                                       \
            _Pragma("unroll")                                                   \
            for (int o = 0; o < 8; o++) {                                       \
                const float* w0r = P_ + OW0 + o * 10;                           \
                const float base = P_[OB0 + o] + w0r[1] * (X1);                 \
                const float w0  = w0r[0];                                       \
                const float wc0 = w0r[2], wc1 = w0r[3], wc2 = w0r[4],           \
                            wc3 = w0r[5], wc4 = w0r[6], wc5 = w0r[7],           \
                            wc6 = w0r[8], wc7 = w0r[9];                         \
                float a0 = base + w0 * X0V[0]                                   \
                         + wc0 * f0.x + wc1 * f1.x + wc2 * f2.x + wc3 * f3.x    \
                         + wc4 * f4.x + wc5 * f5.x + wc6 * f6.x + wc7 * f7.x;   \
                float a1 = base + w0 * X0V[1]                                   \
                         + wc0 * f0.y + wc1 * f1.y + wc2 * f2.y + wc3 * f3.y    \
                         + wc4 * f4.y + wc5 * f5.y + wc6 * f6.y + wc7 * f7.y;   \
                float a2 = base + w0 * X0V[2]                                   \
                         + wc0 * f0.z + wc1 * f1.z + wc2 * f2.z + wc3 * f3.z    \
                         + wc4 * f4.z + wc5 * f5.z + wc6 * f6.z + wc7 * f7.z;   \
                float a3 = base + w0 * X0V[3]                                   \
                         + wc0 * f0.w + wc1 * f1.w + wc2 * f2.w + wc3 * f3.w    \
                         + wc4 * f4.w + wc5 * f5.w + wc6 * f6.w + wc7 * f7.w;   \
                M0A[o] = fmaxf(M0A[o], fmaxf(a0, a1));                          \
                M0B[o] = fmaxf(M0B[o], fmaxf(a2, a3));                          \
            }                                                                   \
        }
        L0_HEAD(PA, x0A, x1A, m0aA, m0bA)
        L0_HEAD(PB, x0B, x1B, m0aB, m0bB)
#undef L0_HEAD
    }

    // ---- conv1 (relu) + pool over qx (local) and qy (cross-lane), per head -
#define L1_HEAD(P_, M0A, M0B, HID)                                              \
    {                                                                           \
        _Pragma("unroll")                                                       \
        for (int o = 0; o < 8; o++) {                                           \
            float a = P_[OB1 + o];                                              \
            float b = a;                                                        \
            _Pragma("unroll")                                                   \
            for (int c = 0; c < 8; c++) {                                       \
                const float w = P_[OW1 + o * 8 + c];                            \
                a += w * M0A[c];                                                \
                b += w * M0B[c];                                                \
            }                                                                   \
            const float h = fmaxf(fmaxf(a, b), 0.0f);                           \
            const float m = fmaxf(h, __shfl_xor(h, 32, 64));                    \
            if (qy == HID) s_m1[HID][pix][o] = m;                               \
        }                                                                       \
    }
    L1_HEAD(PA, m0aA, m0bA, 0)
    L1_HEAD(PB, m0aB, m0bB, 1)
#undef L1_HEAD
    __syncthreads();

    // ---- conv2 (relu): one output channel per thread, both heads ----------
    const int o = tid;                        // output channel 0..63
#define L2_HEAD(P_, HID)                                                        \
    {                                                                           \
        const float4 wa = *(const float4*)(P_ + OW2 + o * 8);                   \
        const float4 wb = *(const float4*)(P_ + OW2 + o * 8 + 4);               \
        const float  bo = P_[OB2 + o];                                          \
        float accum = 0.0f;                                                     \
        _Pragma("unroll 4")                                                     \
        for (int p2 = 0; p2 < CPIX; p2++) {                                     \
            const float4 va = *(const float4*)&s_m1[HID][p2][0];                \
            const float4 vb = *(const float4*)&s_m1[HID][p2][4];                \
            float a = bo + wa.x * va.x + wa.y * va.y + wa.z * va.z              \
                         + wa.w * va.w + wb.x * vb.x + wb.y * vb.y              \
                         + wb.z * vb.z + wb.w * vb.w;                           \
            accum += fmaxf(a, 0.0f);                                            \
        }                                                                       \
        ws_part[(((size_t)inst * 2 + HID) * NCHUNK + chunk) * 64 + o] = accum;  \
    }
    L2_HEAD(PA, 0)
    L2_HEAD(PB, 1)
#undef L2_HEAD

    // ---- completion protocol: last block of this inst runs the MLPs -------
    __threadfence();                          // release: partials -> LLC
    unsigned old = 0u;
    if (tid == 0) old = atomicAdd(&cnt[inst], 1u);
    old = __shfl(old, 0, 64);
    if (old % NCHUNK != (NCHUNK - 1)) return; // exactly one winner per inst
    __threadfence();                          // acquire: invalidate stale L1/L2

    // ---- MLP for both heads with 64 threads -------------------------------
    #pragma unroll 1
    for (int head = 0; head < 2; head++) {
        const float* __restrict__ w1h = head ? sw1 : mw1;
        const float* __restrict__ b1h = head ? sb1 : mb1;
        const float* __restrict__ gh  = head ? sg  : mg;
        const float* __restrict__ bth = head ? sbeta : mbeta;
        const float* __restrict__ w2h = head ? sw2 : mw2;
        const float* __restrict__ b2h = head ? sb2 : mb2;

        // spatial mean: thread t sums channel t over the 30 chunk-partials
        {
            const float* basep =
                ws_part + ((size_t)inst * 2 + head) * NCHUNK * 64 + tid;
            float xm = 0.0f;
            #pragma unroll
            for (int q = 0; q < NCHUNK; q++) xm += basep[q * 64];
            s_x[tid] = xm * (1.0f / (float)NPIX);
        }
        __syncthreads();

        // fc1: thread t computes rows t and t+64
        float a0, a1;
        {
            const float* wr0 = w1h + tid * 64;
            const float* wr1 = w1h + (tid + 64) * 64;
            a0 = b1h[tid];
            a1 = b1h[tid + 64];
            #pragma unroll
            for (int k = 0; k < 16; k++) {
                const float4 xv = *(const float4*)(&s_x[k * 4]);
                const float4 w0v = *(const float4*)(wr0 + k * 4);
                const float4 w1v = *(const float4*)(wr1 + k * 4);
                a0 += w0v.x * xv.x + w0v.y * xv.y + w0v.z * xv.z + w0v.w * xv.w;
                a1 += w1v.x * xv.x + w1v.y * xv.y + w1v.z * xv.z + w1v.w * xv.w;
            }
        }
        // LayerNorm over 128 (both values per thread, one-wave butterfly)
        float s = a0 + a1;
        #pragma unroll
        for (int m = 32; m >= 1; m >>= 1) s += __shfl_xor(s, m, 64);
        const float mu = s * (1.0f / 128.0f);
        const float d0 = a0 - mu, d1 = a1 - mu;
        float s2 = d0 * d0 + d1 * d1;
        #pragma unroll
        for (int m = 32; m >= 1; m >>= 1) s2 += __shfl_xor(s2, m, 64);
        const float rinv = 1.0f / sqrtf(s2 * (1.0f / 128.0f) + 1e-5f);

        const float hn0 = d0 * rinv * gh[tid] + bth[tid];
        const float hn1 = d1 * rinv * gh[tid + 64] + bth[tid + 64];
        const float sv0 = (hn0 > 0.0f) ? SELU_SCALE * hn0
                          : SELU_SCALE * SELU_ALPHA * (expf(hn0) - 1.0f);
        const float sv1 = (hn1 > 0.0f) ? SELU_SCALE * hn1
                          : SELU_SCALE * SELU_ALPHA * (expf(hn1) - 1.0f);
        s_h[tid] = sv0;
        s_h[tid + 64] = sv1;
        __syncthreads();

        // fc2: thread t computes output t
        {
            const float* wr = w2h + tid * 128;
            float a = b2h[tid];
            #pragma unroll
            for (int k = 0; k < 32; k++) {
                const float4 wv = *(const float4*)(wr + k * 4);
                const float4 hv = *(const float4*)(&s_h[k * 4]);
                a += wv.x * hv.x + wv.y * hv.y + wv.z * hv.z + wv.w * hv.w;
            }
            out[(size_t)head * (size_t)n_inst * 64 + (size_t)inst * 64 + tid] = a;
        }
        __syncthreads();   // protect s_x/s_h reuse for head 1
    }
}

extern "C" void kernel_launch(void* const* d_in, const int* in_sizes, int n_in,
                              void* d_out, int out_size, void* d_ws, size_t ws_size,
                              hipStream_t stream) {
    const float* mask_feats  = (const float*)d_in[0];
    const float* pmain       = (const float*)d_in[1];
    const float* pside       = (const float*)d_in[2];
    const int*   im_inds     = (const int*)  d_in[3];
    const float* inst_loc    = (const float*)d_in[4];
    const float* offset_pred = (const float*)d_in[5];
    const int*   fpn_levels  = (const int*)  d_in[6];
    const float* mw1   = (const float*)d_in[7];
    const float* mb1   = (const float*)d_in[8];
    const float* mg    = (const float*)d_in[9];
    const float* mbeta = (const float*)d_in[10];
    const float* mw2   = (const float*)d_in[11];
    const float* mb2   = (const float*)d_in[12];
    const float* sw1   = (const float*)d_in[13];
    const float* sb1   = (const float*)d_in[14];
    const float* sg    = (const float*)d_in[15];
    const float* sbeta = (const float*)d_in[16];
    const float* sw2   = (const float*)d_in[17];
    const float* sb2   = (const float*)d_in[18];
    const int*   strid = (const int*)  d_in[19];
    float* out = (float*)d_out;

    const int n_inst = in_sizes[3];   // im_inds length

    float*    ws_part = (float*)d_ws;                       // ~1.97 MB used
    unsigned* cnt = (unsigned*)((char*)d_ws + ((size_t)n_inst * 2 * NCHUNK * 64) * sizeof(float));
    // cnt is NEVER zeroed: winner = (old % NCHUNK == NCHUNK-1) holds for any
    // starting value; exactly one winner per inst per call.

    dim3 g1(n_inst, NCHUNK);
    track_head_fused<<<g1, 64, 0, stream>>>(
        mask_feats, pmain, pside, im_inds, inst_loc, offset_pred, fpn_levels,
        strid,
        mw1, mb1, mg, mbeta, mw2, mb2,
        sw1, sb1, sg, sbeta, sw2, sb2,
        ws_part, cnt, out, n_inst);
}

// Round 11
// 27.908 us; speedup vs baseline: 3.4099x; 3.4099x over previous
//
#include <hip/hip_runtime.h>
#include <math.h>

// DynamicTrackHead — R11: R9 two-kernel structure + packed-fp32 (v_pk_fma_f32)
// conv tower. conv0/conv1 pack along qx column-pairs (same scalar weight ->
// one SGPR read; feature pairs = adjacent halves of float4 loads); conv2
// packs along heads with float2-interleaved LDS ([8][32][2]) halving
// ds_read_b128 count (128->64) and conv2 VALU. K2 (MLP) unchanged from R9.
// K1: grid (n_inst, NCHUNK=30), block 64 = one wave, 2 thr/pooled-pixel.
// params/instance = 736 floats: w0[8][10]@0, w1[8][8]@80, w2[64][8]@144,
// b0@656, b1@664, b2@672.

#define H_IN 96
#define W_IN 160
#define HW_IN (H_IN * W_IN)
#define PW 40            // W_IN / 4
#define PH 24            // H_IN / 4
#define NPIX (PH * PW)   // 960 pooled-twice pixels
#define NCHUNK 30        // K1 blocks per instance
#define CPIX 32          // pooled pixels per K1 block
#define NPARAM 736
#define OW0 0
#define OW1 80
#define OW2 144
#define OB0 656
#define OB1 664
#define OB2 672

#define SELU_SCALE 1.0507009873554805f
#define SELU_ALPHA 1.6732632423543772f

// packed-fp32 helpers: component-wise fmaf/fmaxf on float2 -> SLP vectorizer
// forms v_pk_fma_f32 / v_pk_max_f32 on gfx950 (full-rate dual fp32).
static __device__ __forceinline__ float2 pk_fma(float s, float2 v, float2 acc) {
    return make_float2(fmaf(s, v.x, acc.x), fmaf(s, v.y, acc.y));
}
static __device__ __forceinline__ float2 pk_max(float2 a, float2 b) {
    return make_float2(fmaxf(a.x, b.x), fmaxf(a.y, b.y));
}
static __device__ __forceinline__ float2 pk_add(float2 a, float2 b) {
    return make_float2(a.x + b.x, a.y + b.y);
}

// ---------------------------------------------------------------------------
// K1: conv tower for BOTH heads + partial spatial sums. One wave per block.
// ---------------------------------------------------------------------------
__global__ __launch_bounds__(64, 4) void track_head_conv(
    const float* __restrict__ mask_feats,
    const float* __restrict__ pmain,
    const float* __restrict__ pside,
    const int*   __restrict__ im_inds,
    const float* __restrict__ inst_loc,
    const float* __restrict__ offset_pred,
    const int*   __restrict__ fpn_levels,
    const int*   __restrict__ stride_ptr,
    float*       __restrict__ ws_part)      // [n_inst][2][NCHUNK][64]
{
    const int inst  = blockIdx.x;
    const int chunk = blockIdx.y;
    const int tid   = threadIdx.x;          // 0..63
    const int pix   = tid & 31;             // pixel within chunk
    const int qy    = tid >> 5;             // which pool-2 row half

    // [channel][pixel][head] float -> float2 (head-pair) reads are contiguous.
    __shared__ float s_m1[8][CPIX][2];      // 2 KB

    const float* __restrict__ PA = pmain + (size_t)inst * NPARAM;
    const float* __restrict__ PB = pside + (size_t)inst * NPARAM;

    const int S  = stride_ptr[0];
    const int S2 = S / 2;
    const float lxA = inst_loc[inst * 2 + 0];
    const float lyA = inst_loc[inst * 2 + 1];
    const float lxB = lxA + offset_pred[inst * 2 + 0] * 128.0f;
    const float lyB = lyA + offset_pred[inst * 2 + 1] * 128.0f;
    const float inv_soi = 1.0f / (float)(64 << fpn_levels[inst]);
    const float* __restrict__ feat =
        mask_feats + (size_t)im_inds[inst] * 8 * HW_IN;

    const int p   = chunk * CPIX + pix;     // 0..959
    const int py  = p / PW;
    const int px  = p - py * PW;
    const int ix0 = px * 4;
    const int iyb = py * 4 + qy * 2;        // this thread's two input rows

    // x-coordinate channel values, packed as column pairs (cols 0,1 / 2,3)
    float2 x0A01, x0A23, x0B01, x0B23;
    {
        const float xc0 = (float)(ix0 * S + S2);
        const float xc1 = (float)((ix0 + 1) * S + S2);
        const float xc2 = (float)((ix0 + 2) * S + S2);
        const float xc3 = (float)((ix0 + 3) * S + S2);
        x0A01 = make_float2((lxA - xc0) * inv_soi, (lxA - xc1) * inv_soi);
        x0A23 = make_float2((lxA - xc2) * inv_soi, (lxA - xc3) * inv_soi);
        x0B01 = make_float2((lxB - xc0) * inv_soi, (lxB - xc1) * inv_soi);
        x0B23 = make_float2((lxB - xc2) * inv_soi, (lxB - xc3) * inv_soi);
    }

    // ---- conv0 (relu folded into max): q*[o] = (quad-a, quad-b) pooled -----
    float2 qA[8], qB[8];                    // x = cols{0,1} quad, y = cols{2,3}
    #pragma unroll
    for (int o = 0; o < 8; o++) { qA[o] = make_float2(0.f, 0.f);
                                  qB[o] = make_float2(0.f, 0.f); }

    #pragma unroll
    for (int sy = 0; sy < 2; sy++) {
        const int iy = iyb + sy;
        const float yc = (float)(iy * S + S2);
        const float x1A = (lyA - yc) * inv_soi;
        const float x1B = (lyB - yc) * inv_soi;
        const float* rowp = feat + iy * W_IN + ix0;
        const float4 f0 = *(const float4*)(rowp + 0 * HW_IN);
        const float4 f1 = *(const float4*)(rowp + 1 * HW_IN);
        const float4 f2 = *(const float4*)(rowp + 2 * HW_IN);
        const float4 f3 = *(const float4*)(rowp + 3 * HW_IN);
        const float4 f4 = *(const float4*)(rowp + 4 * HW_IN);
        const float4 f5 = *(const float4*)(rowp + 5 * HW_IN);
        const float4 f6 = *(const float4*)(rowp + 6 * HW_IN);
        const float4 f7 = *(const float4*)(rowp + 7 * HW_IN);
        // adjacent column pairs of each channel row (register halves)
        const float2 g0a = make_float2(f0.x, f0.y), g0b = make_float2(f0.z, f0.w);
        const float2 g1a = make_float2(f1.x, f1.y), g1b = make_float2(f1.z, f1.w);
        const float2 g2a = make_float2(f2.x, f2.y), g2b = make_float2(f2.z, f2.w);
        const float2 g3a = make_float2(f3.x, f3.y), g3b = make_float2(f3.z, f3.w);
        const float2 g4a = make_float2(f4.x, f4.y), g4b = make_float2(f4.z, f4.w);
        const float2 g5a = make_float2(f5.x, f5.y), g5b = make_float2(f5.z, f5.w);
        const float2 g6a = make_float2(f6.x, f6.y), g6b = make_float2(f6.z, f6.w);
        const float2 g7a = make_float2(f7.x, f7.y), g7b = make_float2(f7.z, f7.w);

#define L0_HEAD(P_, X01, X23, X1, QARR)                                         \
        {                                                                       \
            _Pragma("unroll")                                                   \
            for (int o = 0; o < 8; o++) {                                       \
                const float* w0r = P_ + OW0 + o * 10;                           \
                const float base = P_[OB0 + o] + w0r[1] * (X1);                 \
                const float w0  = w0r[0];                                       \
                float2 a01 = make_float2(base, base);                           \
                float2 a23 = make_float2(base, base);                           \
                a01 = pk_fma(w0, X01, a01);      a23 = pk_fma(w0, X23, a23);    \
                a01 = pk_fma(w0r[2], g0a, a01);  a23 = pk_fma(w0r[2], g0b, a23);\
                a01 = pk_fma(w0r[3], g1a, a01);  a23 = pk_fma(w0r[3], g1b, a23);\
                a01 = pk_fma(w0r[4], g2a, a01);  a23 = pk_fma(w0r[4], g2b, a23);\
                a01 = pk_fma(w0r[5], g3a, a01);  a23 = pk_fma(w0r[5], g3b, a23);\
                a01 = pk_fma(w0r[6], g4a, a01);  a23 = pk_fma(w0r[6], g4b, a23);\
                a01 = pk_fma(w0r[7], g5a, a01);  a23 = pk_fma(w0r[7], g5b, a23);\
                a01 = pk_fma(w0r[8], g6a, a01);  a23 = pk_fma(w0r[8], g6b, a23);\
                a01 = pk_fma(w0r[9], g7a, a01);  a23 = pk_fma(w0r[9], g7b, a23);\
                /* pool within column pairs (horizontal max), relu via init */  \
                QARR[o].x = fmaxf(QARR[o].x, fmaxf(a01.x, a01.y));              \
                QARR[o].y = fmaxf(QARR[o].y, fmaxf(a23.x, a23.y));              \
            }                                                                   \
        }
        L0_HEAD(PA, x0A01, x0A23, x1A, qA)
        L0_HEAD(PB, x0B01, x0B23, x1B, qB)
#undef L0_HEAD
    }

    // ---- conv1 (relu) packed over quads; pool qx (horizontal) + qy (shfl) --
#define L1_HEAD(P_, QARR, HID)                                                  \
    {                                                                           \
        _Pragma("unroll")                                                       \
        for (int o = 0; o < 8; o++) {                                           \
            const float b1o = P_[OB1 + o];                                      \
            float2 acc = make_float2(b1o, b1o);                                 \
            _Pragma("unroll")                                                   \
            for (int c = 0; c < 8; c++)                                         \
                acc = pk_fma(P_[OW1 + o * 8 + c], QARR[c], acc);                \
            const float h = fmaxf(fmaxf(acc.x, acc.y), 0.0f);                   \
            const float m = fmaxf(h, __shfl_xor(h, 32, 64));                    \
            if (qy == HID) s_m1[o][pix][HID] = m;                               \
        }                                                                       \
    }
    L1_HEAD(PA, qA, 0)
    L1_HEAD(PB, qB, 1)
#undef L1_HEAD
    __syncthreads();

    // ---- conv2 (relu) packed over heads: one output channel per thread -----
    {
        const int o = tid;                    // output channel 0..63
        float2 w2pk[8];
        #pragma unroll
        for (int c = 0; c < 8; c++)
            w2pk[c] = make_float2(PA[OW2 + o * 8 + c], PB[OW2 + o * 8 + c]);
        const float2 bo = make_float2(PA[OB2 + o], PB[OB2 + o]);
        const float2 zero = make_float2(0.f, 0.f);
        float2 accum = zero;
        #pragma unroll 2
        for (int j = 0; j < 8; j++) {         // 4 pixels per iteration
            // rd[c] = heads-interleaved values of channel c for px 4j..4j+3
            float4 rd[8];
            #pragma unroll
            for (int c = 0; c < 8; c++)
                rd[c] = *(const float4*)&s_m1[c][4 * j][0];   // broadcast read
            float2 aP0 = bo, aP1 = bo;        // px 4j,4j+1 ... wait: see below
            // rd[c].xy = (A,B) of px 4j   ; rd[c].zw = (A,B) of px 4j+1
            // next 2 px come from the second half of the 16B? No: 16B covers
            // px 4j and 4j+1 only (2 px * 2 heads * 4B). Use two reads.
            float4 rd2[8];
            #pragma unroll
            for (int c = 0; c < 8; c++)
                rd2[c] = *(const float4*)&s_m1[c][4 * j + 2][0];
            float2 aP2 = bo, aP3 = bo;
            #pragma unroll
            for (int c = 0; c < 8; c++) {
                aP0 = pk_fma(w2pk[c].x, make_float2(rd[c].x, rd[c].x), aP0);  // placeholder, replaced below
            }
            // NOTE: head-packed accumulation done explicitly:
            aP0 = bo; aP1 = bo; aP2 = bo; aP3 = bo;
            #pragma unroll
            for (int c = 0; c < 8; c++) {
                const float2 hA0 = make_float2(rd[c].x,  rd[c].y);   // px 4j
                const float2 hA1 = make_float2(rd[c].z,  rd[c].w);   // px 4j+1
                const float2 hA2 = make_float2(rd2[c].x, rd2[c].y);  // px 4j+2
                const float2 hA3 = make_float2(rd2[c].z, rd2[c].w);  // px 4j+3
                // (A,B) pair times per-head weight pair:
                aP0 = make_float2(fmaf(w2pk[c].x, hA0.x, aP0.x),
                                  fmaf(w2pk[c].y, hA0.y, aP0.y));
                aP1 = make_float2(fmaf(w2pk[c].x, hA1.x, aP1.x),
                                  fmaf(w2pk[c].y, hA1.y, aP1.y));
                aP2 = make_float2(fmaf(w2pk[c].x, hA2.x, aP2.x),
                                  fmaf(w2pk[c].y, hA2.y, aP2.y));
                aP3 = make_float2(fmaf(w2pk[c].x, hA3.x, aP3.x),
                                  fmaf(w2pk[c].y, hA3.y, aP3.y));
            }
            accum = pk_add(accum, pk_max(aP0, zero));
            accum = pk_add(accum, pk_max(aP1, zero));
            accum = pk_add(accum, pk_max(aP2, zero));
            accum = pk_add(accum, pk_max(aP3, zero));
        }
        float* wsb = ws_part + (((size_t)inst * 2 + 0) * NCHUNK + chunk) * 64;
        wsb[o] = accum.x;
        wsb[NCHUNK * 64 + o] = accum.y;
    }
}

// ---------------------------------------------------------------------------
// K2: combine partials -> mean -> MLP (fc1 -> LN -> SELU -> fc2) -> logits
// ---------------------------------------------------------------------------
__global__ __launch_bounds__(128) void track_head_mlp(
    const float* __restrict__ ws_part,
    const float* __restrict__ mw1, const float* __restrict__ mb1,
    const float* __restrict__ mg,  const float* __restrict__ mbeta,
    const float* __restrict__ mw2, const float* __restrict__ mb2,
    const float* __restrict__ sw1, const float* __restrict__ sb1,
    const float* __restrict__ sg,  const float* __restrict__ sbeta,
    const float* __restrict__ sw2, const float* __restrict__ sb2,
    float*       __restrict__ out,
    int n_inst)
{
    const int inst = blockIdx.x;
    const int head = blockIdx.y;
    const int tid  = threadIdx.x;
    const int lane = tid & 63;
    const int wid  = tid >> 6;

    __shared__ __align__(16) float s_x[64];
    __shared__ __align__(16) float s_h[128];
    __shared__ float s_r[4];

    if (tid < 64) {
        const float* base = ws_part + ((size_t)inst * 2 + head) * NCHUNK * 64 + tid;
        float xm = 0.0f;
        #pragma unroll
        for (int q = 0; q < NCHUNK; q++) xm += base[q * 64];
        s_x[tid] = xm * (1.0f / (float)NPIX);
    }
    __syncthreads();

    const float* __restrict__ w1h = head ? sw1 : mw1;
    const float* __restrict__ b1h = head ? sb1 : mb1;
    const float* __restrict__ gh  = head ? sg  : mg;
    const float* __restrict__ bth = head ? sbeta : mbeta;
    const float* __restrict__ w2h = head ? sw2 : mw2;
    const float* __restrict__ b2h = head ? sb2 : mb2;

    float hval = 0.0f, dval = 0.0f;
    {
        const float* wr = w1h + tid * 64;
        float a = b1h[tid];
        #pragma unroll
        for (int k = 0; k < 16; k++) {
            const float4 wv = *(const float4*)(wr + k * 4);
            const float4 xv = *(const float4*)(&s_x[k * 4]);
            a += wv.x * xv.x + wv.y * xv.y + wv.z * xv.z + wv.w * xv.w;
        }
        hval = a;
    }
    {
        float s = hval;
        #pragma unroll
        for (int m = 32; m >= 1; m >>= 1) s += __shfl_xor(s, m, 64);
        if (lane == 0) s_r[wid] = s;
    }
    __syncthreads();
    const float mu = (s_r[0] + s_r[1]) * (1.0f / 128.0f);
    dval = hval - mu;
    {
        float s = dval * dval;
        #pragma unroll
        for (int m = 32; m >= 1; m >>= 1) s += __shfl_xor(s, m, 64);
        if (lane == 0) s_r[wid + 2] = s;
    }
    __syncthreads();
    const float var = (s_r[2] + s_r[3]) * (1.0f / 128.0f);

    {
        const float hn = dval * (1.0f / sqrtf(var + 1e-5f)) * gh[tid] + bth[tid];
        const float sv = (hn > 0.0f)
                           ? SELU_SCALE * hn
                           : SELU_SCALE * SELU_ALPHA * (expf(hn) - 1.0f);
        s_h[tid] = sv;
    }
    __syncthreads();

    if (tid < 64) {
        const float* wr = w2h + tid * 128;
        float a = b2h[tid];
        #pragma unroll
        for (int k = 0; k < 32; k++) {
            const float4 wv = *(const float4*)(wr + k * 4);
            const float4 hv = *(const float4*)(&s_h[k * 4]);
            a += wv.x * hv.x + wv.y * hv.y + wv.z * hv.z + wv.w * hv.w;
        }
        out[(size_t)head * (size_t)n_inst * 64 + (size_t)inst * 64 + tid] = a;
    }
}

extern "C" void kernel_launch(void* const* d_in, const int* in_sizes, int n_in,
                              void* d_out, int out_size, void* d_ws, size_t ws_size,
                              hipStream_t stream) {
    const float* mask_feats  = (const float*)d_in[0];
    const float* pmain       = (const float*)d_in[1];
    const float* pside       = (const float*)d_in[2];
    const int*   im_inds     = (const int*)  d_in[3];
    const float* inst_loc    = (const float*)d_in[4];
    const float* offset_pred = (const float*)d_in[5];
    const int*   fpn_levels  = (const int*)  d_in[6];
    const float* mw1   = (const float*)d_in[7];
    const float* mb1   = (const float*)d_in[8];
    const float* mg    = (const float*)d_in[9];
    const float* mbeta = (const float*)d_in[10];
    const float* mw2   = (const float*)d_in[11];
    const float* mb2   = (const float*)d_in[12];
    const float* sw1   = (const float*)d_in[13];
    const float* sb1   = (const float*)d_in[14];
    const float* sg    = (const float*)d_in[15];
    const float* sbeta = (const float*)d_in[16];
    const float* sw2   = (const float*)d_in[17];
    const float* sb2   = (const float*)d_in[18];
    const int*   strid = (const int*)  d_in[19];
    float* out = (float*)d_out;

    const int n_inst = in_sizes[3];   // im_inds length
    float* ws_part = (float*)d_ws;    // n_inst*2*NCHUNK*64 floats ~= 2 MB

    dim3 g1(n_inst, NCHUNK);
    track_head_conv<<<g1, 64, 0, stream>>>(
        mask_feats, pmain, pside, im_inds, inst_loc, offset_pred, fpn_levels,
        strid, ws_part);

    dim3 g2(n_inst, 2);
    track_head_mlp<<<g2, 128, 0, stream>>>(
        ws_part,
        mw1, mb1, mg, mbeta, mw2, mb2,
        sw1, sb1, sg, sbeta, sw2, sb2,
        out, n_inst);
}